// Round 1
// baseline (30.513 us; speedup 1.0000x reference)
//
#include <hip/hip_runtime.h>
#include <hip/hip_bf16.h>

// Problem: B=64, C=512, Q=64, D=512, fp32 in/out.
// out[b,c,q] = sum_d (H[b,c,d]*w_hu[d]) * U[b,q,d] + s_h[b,c] + s_u[b,q]
// s_h[b,c] = sum_d H[b,c,d]*w_h[d];  s_u[b,q] = sum_d U[b,q,d]*w_u[d]
// w layout: w[0:512]=w_h, w[512:1024]=w_u, w[1024:1536]=w_hu

#define Bdim 64
#define Cdim 512
#define Qdim 64
#define Ddim 512

#define BM 64
#define BN 64
#define BK 64
#define LDK 72   // +8 bf16 pad -> 144B row stride, breaks bank conflicts
#define NK (Ddim / BK)   // 8

typedef __bf16 bf16x8 __attribute__((ext_vector_type(8)));
typedef float  f32x4  __attribute__((ext_vector_type(4)));

__global__ __launch_bounds__(256, 2)
void sim_kernel(const float* __restrict__ H, const float* __restrict__ U,
                const float* __restrict__ w, float* __restrict__ out)
{
    __shared__ __bf16 As[2][BM * LDK];
    __shared__ __bf16 Bs[2][BN * LDK];
    __shared__ float  sh_l[BM];
    __shared__ float  su_l[BN];

    const int b  = blockIdx.x >> 3;   // batch
    const int mt = blockIdx.x & 7;    // m-tile
    const int m0 = mt * BM;

    const int t   = threadIdx.x;
    const int row = t >> 2;           // 0..63: c-row (A) / q-row (B)
    const int seg = t & 3;            // 0..3: 16-col segment within BK

    const float* __restrict__ Hrow = H + ((size_t)(b * Cdim + m0 + row)) * Ddim + seg * 16;
    const float* __restrict__ Urow = U + ((size_t)(b * Qdim + row)) * Ddim + seg * 16;
    const float* __restrict__ wh  = w;
    const float* __restrict__ wu  = w + 512;
    const float* __restrict__ whu = w + 1024;

    float sh_p = 0.f, su_p = 0.f;

    f32x4 hv[4], uv[4];

    // ---- staging helpers ----
    auto load_step = [&](int ks) {
        const float* hp = Hrow + ks * BK;
        const float* up = Urow + ks * BK;
#pragma unroll
        for (int i = 0; i < 4; ++i) {
            hv[i] = *(const f32x4*)(hp + 4 * i);
            uv[i] = *(const f32x4*)(up + 4 * i);
        }
    };

    auto stage_step = [&](int ks, int buf) {
        const int c0 = ks * BK + seg * 16;
        __bf16 ab[16], bb[16];
#pragma unroll
        for (int i = 0; i < 4; ++i) {
            f32x4 whv  = *(const f32x4*)(wh  + c0 + 4 * i);
            f32x4 wuv  = *(const f32x4*)(wu  + c0 + 4 * i);
            f32x4 whuv = *(const f32x4*)(whu + c0 + 4 * i);
#pragma unroll
            for (int j = 0; j < 4; ++j) {
                float h = hv[i][j], u = uv[i][j];
                sh_p += h * whv[j];
                su_p += u * wuv[j];
                ab[4 * i + j] = (__bf16)(h * whuv[j]);
                bb[4 * i + j] = (__bf16)u;
            }
        }
        __bf16* ad = &As[buf][row * LDK + seg * 16];
        __bf16* bd = &Bs[buf][row * LDK + seg * 16];
        *(bf16x8*)(ad)     = *(bf16x8*)(ab);
        *(bf16x8*)(ad + 8) = *(bf16x8*)(ab + 8);
        *(bf16x8*)(bd)     = *(bf16x8*)(bb);
        *(bf16x8*)(bd + 8) = *(bf16x8*)(bb + 8);
    };

    // ---- compute setup ----
    const int wv   = t >> 6;          // wave 0..3
    const int lane = t & 63;
    const int wr = (wv >> 1) * 32;    // wave row offset in tile
    const int wc = (wv & 1) * 32;     // wave col offset
    const int lr = lane & 15;         // fragment row (A) / col (B)
    const int lk = (lane >> 4) * 8;   // fragment k offset

    f32x4 acc[2][2] = {};

    auto compute_step = [&](int buf) {
#pragma unroll
        for (int kk = 0; kk < 2; ++kk) {
            bf16x8 a0 = *(const bf16x8*)&As[buf][(wr +  0 + lr) * LDK + kk * 32 + lk];
            bf16x8 a1 = *(const bf16x8*)&As[buf][(wr + 16 + lr) * LDK + kk * 32 + lk];
            bf16x8 b0 = *(const bf16x8*)&Bs[buf][(wc +  0 + lr) * LDK + kk * 32 + lk];
            bf16x8 b1 = *(const bf16x8*)&Bs[buf][(wc + 16 + lr) * LDK + kk * 32 + lk];
            acc[0][0] = __builtin_amdgcn_mfma_f32_16x16x32_bf16(a0, b0, acc[0][0], 0, 0, 0);
            acc[0][1] = __builtin_amdgcn_mfma_f32_16x16x32_bf16(a0, b1, acc[0][1], 0, 0, 0);
            acc[1][0] = __builtin_amdgcn_mfma_f32_16x16x32_bf16(a1, b0, acc[1][0], 0, 0, 0);
            acc[1][1] = __builtin_amdgcn_mfma_f32_16x16x32_bf16(a1, b1, acc[1][1], 0, 0, 0);
        }
    };

    // ---- main loop: reg-prefetch + LDS double buffer ----
    load_step(0);
    stage_step(0, 0);
    __syncthreads();

    for (int ks = 0; ks < NK; ++ks) {
        if (ks + 1 < NK) load_step(ks + 1);
        compute_step(ks & 1);
        if (ks + 1 < NK) {
            __syncthreads();
            stage_step(ks + 1, (ks + 1) & 1);
            __syncthreads();
        }
    }

    // ---- s_h / s_u reduction (4 adjacent lanes share a row) ----
    sh_p += __shfl_xor(sh_p, 1);
    sh_p += __shfl_xor(sh_p, 2);
    su_p += __shfl_xor(su_p, 1);
    su_p += __shfl_xor(su_p, 2);
    if (seg == 0) { sh_l[row] = sh_p; su_l[row] = su_p; }
    __syncthreads();

    // ---- epilogue: D row = (lane>>4)*4 + r, col = lane&15 (per fragment) ----
    float* __restrict__ outb = out + ((size_t)(b * Cdim + m0)) * Qdim;
#pragma unroll
    for (int fm = 0; fm < 2; ++fm) {
#pragma unroll
        for (int fn = 0; fn < 2; ++fn) {
            const int colq  = wc + fn * 16 + (lane & 15);
            const int rbase = wr + fm * 16 + (lane >> 4) * 4;
#pragma unroll
            for (int r = 0; r < 4; ++r) {
                const int rr = rbase + r;
                outb[(size_t)rr * Qdim + colq] = acc[fm][fn][r] + sh_l[rr] + su_l[colq];
            }
        }
    }
}

extern "C" void kernel_launch(void* const* d_in, const int* in_sizes, int n_in,
                              void* d_out, int out_size, void* d_ws, size_t ws_size,
                              hipStream_t stream) {
    const float* H = (const float*)d_in[0];
    const float* U = (const float*)d_in[1];
    const float* w = (const float*)d_in[2];
    float* out = (float*)d_out;
    sim_kernel<<<dim3(Bdim * (Cdim / BM)), dim3(256), 0, stream>>>(H, U, w, out);
}

// Round 2
// 23.766 us; speedup vs baseline: 1.2839x; 1.2839x over previous
//
#include <hip/hip_runtime.h>
#include <hip/hip_bf16.h>

// B=64, C=512, Q=64, D=512, fp32 in/out.
// out[b,c,q] = sum_d H[b,c,d]*U'[b,q,d] + s_u[b,q]
//   where U'[q,d] = w_hu[d]*U[q,d] + w_h[d]   (folds s_h into the GEMM)
//         s_u[q]  = sum_d w_u[d]*U[q,d]
// w layout: w[0:512]=w_h, w[512:1024]=w_u, w[1024:1536]=w_hu

#define Bn 64
#define Cn 512
#define Qn 64
#define Dn 512
#define NKT 16   // Dn/32 K-tiles

typedef __bf16 bf16x8 __attribute__((ext_vector_type(8)));
typedef float  f32x4  __attribute__((ext_vector_type(4)));

__global__ __launch_bounds__(256, 2)
void sim_kernel(const float* __restrict__ H, const float* __restrict__ U,
                const float* __restrict__ w, float* __restrict__ out)
{
    // U' staged once per block, tiled for conflict-free b128 access:
    // U'[q][d] lives at Us[d>>5][(d>>3)&3][q][d&7]
    __shared__ __bf16 Us[NKT][4][Qn][8];   // 64 KB
    __shared__ float  su_l[Qn];

    // XCD-aware remap: all 8 C-chunks of one batch land on the same XCD
    // (blockIdx round-robins across 8 XCDs), so U[b] is an L2 hit 7/8 times.
    const int r     = (int)blockIdx.x;
    const int b     = (r & 7) * 8 + ((r >> 3) & 7);
    const int chunk = r >> 6;
    const int c0    = chunk * 64;

    const int t    = (int)threadIdx.x;
    const int lane = t & 63;
    const int wv   = t >> 6;

    // ---------------- Phase 1: stage U' (bf16) + s_u ----------------
    {
        const int q   = t >> 2;   // 0..63
        const int seg = t & 3;
        const float* __restrict__ Uq = U + ((size_t)(b * Qn + q)) * Dn;
        float su = 0.f;
#pragma unroll
        for (int j = 0; j < 16; ++j) {
            const int cc = seg + 4 * j;    // 8-elem chunk index 0..63
            const int d0 = 8 * cc;
            f32x4 u0  = *(const f32x4*)(Uq + d0);
            f32x4 u1  = *(const f32x4*)(Uq + d0 + 4);
            f32x4 wh0 = *(const f32x4*)(w + d0);
            f32x4 wh1 = *(const f32x4*)(w + d0 + 4);
            f32x4 wu0 = *(const f32x4*)(w + 512 + d0);
            f32x4 wu1 = *(const f32x4*)(w + 512 + d0 + 4);
            f32x4 wm0 = *(const f32x4*)(w + 1024 + d0);
            f32x4 wm1 = *(const f32x4*)(w + 1024 + d0 + 4);
            bf16x8 v;
#pragma unroll
            for (int i = 0; i < 4; ++i) {
                su += wu0[i] * u0[i];
                su += wu1[i] * u1[i];
                v[i]     = (__bf16)__builtin_fmaf(wm0[i], u0[i], wh0[i]);
                v[i + 4] = (__bf16)__builtin_fmaf(wm1[i], u1[i], wh1[i]);
            }
            *(bf16x8*)&Us[cc >> 2][cc & 3][q][0] = v;
        }
        su += __shfl_xor(su, 1);
        su += __shfl_xor(su, 2);
        if (seg == 0) su_l[q] = su;
    }

    // ---------------- Phase 2: prologue H prefetch (issued before the
    // barrier so HBM latency overlaps the staging drain) ----------------
    const int ql = lane & 15;
    const int hh = lane >> 4;
    const float* __restrict__ hp =
        H + ((size_t)(b * Cn + c0 + wv * 16 + ql)) * Dn + hh * 8;

    f32x4 pa[4], pb[4];
#pragma unroll
    for (int p = 0; p < 3; ++p) {
        pa[p] = *(const f32x4*)(hp + 32 * p);
        pb[p] = *(const f32x4*)(hp + 32 * p + 4);
    }

    __syncthreads();   // the ONLY barrier

    // ---------------- Phase 3: barrier-free K-loop ----------------
    f32x4 acc[4] = {{0.f,0.f,0.f,0.f},{0.f,0.f,0.f,0.f},
                    {0.f,0.f,0.f,0.f},{0.f,0.f,0.f,0.f}};

#pragma unroll
    for (int k = 0; k < NKT; ++k) {   // full unroll: all indices static
        f32x4 ca = pa[k & 3], cb = pb[k & 3];
        if (k + 3 < NKT) {
            pa[(k + 3) & 3] = *(const f32x4*)(hp + 32 * (k + 3));
            pb[(k + 3) & 3] = *(const f32x4*)(hp + 32 * (k + 3) + 4);
        }
        bf16x8 a;
#pragma unroll
        for (int i = 0; i < 4; ++i) {
            a[i]     = (__bf16)ca[i];
            a[i + 4] = (__bf16)cb[i];
        }
        bf16x8 f0 = *(const bf16x8*)&Us[k][hh][ 0 + ql][0];
        bf16x8 f1 = *(const bf16x8*)&Us[k][hh][16 + ql][0];
        bf16x8 f2 = *(const bf16x8*)&Us[k][hh][32 + ql][0];
        bf16x8 f3 = *(const bf16x8*)&Us[k][hh][48 + ql][0];
        acc[0] = __builtin_amdgcn_mfma_f32_16x16x32_bf16(a, f0, acc[0], 0, 0, 0);
        acc[1] = __builtin_amdgcn_mfma_f32_16x16x32_bf16(a, f1, acc[1], 0, 0, 0);
        acc[2] = __builtin_amdgcn_mfma_f32_16x16x32_bf16(a, f2, acc[2], 0, 0, 0);
        acc[3] = __builtin_amdgcn_mfma_f32_16x16x32_bf16(a, f3, acc[3], 0, 0, 0);
    }

    // ---------------- Epilogue: out = acc + s_u[q] ----------------
    float* __restrict__ outb = out + ((size_t)(b * Cn + c0 + wv * 16)) * Qn;
#pragma unroll
    for (int fn = 0; fn < 4; ++fn) {
        const int q = fn * 16 + ql;
        const float s = su_l[q];
#pragma unroll
        for (int rr = 0; rr < 4; ++rr) {
            outb[(size_t)(hh * 4 + rr) * Qn + q] = acc[fn][rr] + s;
        }
    }
}

extern "C" void kernel_launch(void* const* d_in, const int* in_sizes, int n_in,
                              void* d_out, int out_size, void* d_ws, size_t ws_size,
                              hipStream_t stream) {
    const float* H = (const float*)d_in[0];
    const float* U = (const float*)d_in[1];
    const float* w = (const float*)d_in[2];
    float* out = (float*)d_out;
    sim_kernel<<<dim3(Bn * (Cn / 64)), dim3(256), 0, stream>>>(H, U, w, out);
}